// Round 1
// baseline (8319.501 us; speedup 1.0000x reference)
//
#include <hip/hip_runtime.h>
#include <math.h>

#define N_NODES 150000
#define DIM 100
#define D4 25            // DIM/4 float4 chunks
#define T_STEPS 16
#define E_EDGES 262144
#define S_SEEDS 4096
#define K_CAND 9
#define SPB 8            // seeds per LSTM block

__device__ __forceinline__ float sigmoidf_(float x) {
    return 1.0f / (1.0f + __expf(-x));
}

// ---- Kernel A: edge aggregation: agg[dst] += emb[src] * rel_emb[cat]; cnt[dst] += 1
__global__ __launch_bounds__(256) void agg_kernel(
    const float* __restrict__ emb, const float* __restrict__ rel_emb,
    const int* __restrict__ src, const int* __restrict__ dst,
    const int* __restrict__ cat,
    float* __restrict__ agg, float* __restrict__ cnt) {
    int gtid = blockIdx.x * blockDim.x + threadIdx.x;
    int e = gtid / D4;
    int q = gtid - e * D4;
    if (e >= E_EDGES) return;
    int s = src[e], d = dst[e], c = cat[e];
    float4 m = ((const float4*)(emb + (size_t)s * DIM))[q];
    float4 r = ((const float4*)(rel_emb + (size_t)c * DIM))[q];
    float* a = agg + (size_t)d * DIM + q * 4;
    atomicAdd(a + 0, m.x * r.x);
    atomicAdd(a + 1, m.y * r.y);
    atomicAdd(a + 2, m.z * r.z);
    atomicAdd(a + 3, m.w * r.w);
    if (q == 0) atomicAdd(cnt + d, 1.0f);
}

// ---- Kernel G: snapshot pre-update hidden state of seeds
__global__ __launch_bounds__(256) void gather_seed(
    const float* __restrict__ emb, const int* __restrict__ seeds,
    float* __restrict__ h_prev) {
    int i = blockIdx.x * blockDim.x + threadIdx.x;  // over S*D4
    int sd = i / D4, q = i - sd * D4;
    int node = seeds[sd];
    ((float4*)h_prev)[i] = ((const float4*)(emb + (size_t)node * DIM))[q];
}

// ---- Kernel B: emb += agg / max(cnt,1)
__global__ __launch_bounds__(256) void norm_add(
    float* __restrict__ emb, const float* __restrict__ agg,
    const float* __restrict__ cnt) {
    int i = blockIdx.x * blockDim.x + threadIdx.x;  // over N*D4
    if (i >= N_NODES * D4) return;
    int node = i / D4;
    float inv = 1.0f / fmaxf(cnt[node], 1.0f);
    float4 a = ((const float4*)agg)[i];
    float4 e = ((float4*)emb)[i];
    e.x += a.x * inv; e.y += a.y * inv; e.z += a.z * inv; e.w += a.w * inv;
    ((float4*)emb)[i] = e;
}

// ---- Kernel C1: LSTM cell on SPB seeds per block (compute only, no scatter)
__global__ __launch_bounds__(512) void lstm_kernel(
    const float* __restrict__ emb, const float* __restrict__ h_prev,
    const float* __restrict__ c_state, const int* __restrict__ seeds,
    const float* __restrict__ W_ih, const float* __restrict__ W_hh,
    const float* __restrict__ b_ih, const float* __restrict__ b_hh,
    float* __restrict__ h_out, float* __restrict__ c_out) {
    __shared__ float xs[SPB][DIM];
    __shared__ float hs[SPB][DIM];
    __shared__ float gates[SPB][4 * DIM];
    int tid = threadIdx.x;
    int base = blockIdx.x * SPB;

    for (int idx = tid; idx < SPB * DIM; idx += 512) {
        int s = idx / DIM, d = idx - s * DIM;
        int node = seeds[base + s];
        xs[s][d] = emb[(size_t)node * DIM + d];
        hs[s][d] = h_prev[(size_t)(base + s) * DIM + d];
    }
    __syncthreads();

    if (tid < 4 * DIM) {
        int j = tid;
        float acc[SPB];
#pragma unroll
        for (int s = 0; s < SPB; s++) acc[s] = 0.0f;
        const float* wi = W_ih + (size_t)j * DIM;
        const float* wh = W_hh + (size_t)j * DIM;
        for (int d = 0; d < DIM; d++) {
            float a = wi[d], b = wh[d];
#pragma unroll
            for (int s = 0; s < SPB; s++)
                acc[s] += xs[s][d] * a + hs[s][d] * b;
        }
        float bb = b_ih[j] + b_hh[j];
#pragma unroll
        for (int s = 0; s < SPB; s++) gates[s][j] = acc[s] + bb;
    }
    __syncthreads();

    for (int idx = tid; idx < SPB * DIM; idx += 512) {
        int s = idx / DIM, d = idx - s * DIM;
        int node = seeds[base + s];
        float ig = gates[s][d];
        float fg = gates[s][DIM + d];
        float gg = gates[s][2 * DIM + d];
        float og = gates[s][3 * DIM + d];
        float cp = c_state[(size_t)node * DIM + d];
        float cn = sigmoidf_(fg) * cp + sigmoidf_(ig) * tanhf(gg);
        float hn = sigmoidf_(og) * tanhf(cn);
        h_out[(size_t)(base + s) * DIM + d] = hn;
        c_out[(size_t)(base + s) * DIM + d] = cn;
    }
}

// ---- Kernel C2: scatter h_new/c_new back to state (duplicate seeds write identical values)
__global__ __launch_bounds__(256) void scatter_seed(
    float* __restrict__ emb, float* __restrict__ c_state,
    const int* __restrict__ seeds,
    const float* __restrict__ h_new, const float* __restrict__ c_new) {
    int i = blockIdx.x * blockDim.x + threadIdx.x;  // over S*D4
    int sd = i / D4, q = i - sd * D4;
    int node = seeds[sd];
    ((float4*)(emb + (size_t)node * DIM))[q] = ((const float4*)h_new)[i];
    ((float4*)(c_state + (size_t)node * DIM))[q] = ((const float4*)c_new)[i];
}

// ---- Scoring: one wave per user row, 9 candidate dots of length 100
__global__ __launch_bounds__(64) void score_kernel(
    const float* __restrict__ seed_h, const float* __restrict__ emb,
    const int* __restrict__ cand_idx, float* __restrict__ out) {
    int n = blockIdx.x;
    int lane = threadIdx.x;
    float u0 = seed_h[(size_t)n * DIM + lane];           // lane < 64 < 100
    float u1 = (lane + 64 < DIM) ? seed_h[(size_t)n * DIM + lane + 64] : 0.0f;
    for (int k = 0; k < K_CAND; k++) {
        int node = cand_idx[n * K_CAND + k];
        const float* ce = emb + (size_t)node * DIM;
        float p = u0 * ce[lane];
        if (lane + 64 < DIM) p += u1 * ce[lane + 64];
        for (int off = 32; off > 0; off >>= 1) p += __shfl_down(p, off);
        if (lane == 0) out[n * K_CAND + k] = p;
    }
}

extern "C" void kernel_launch(void* const* d_in, const int* in_sizes, int n_in,
                              void* d_out, int out_size, void* d_ws, size_t ws_size,
                              hipStream_t stream) {
    const float* node_emb = (const float*)d_in[0];
    const float* cx       = (const float*)d_in[1];
    const float* rel_emb  = (const float*)d_in[2];
    const float* W_ih     = (const float*)d_in[3];
    const float* W_hh     = (const float*)d_in[4];
    const float* b_ih     = (const float*)d_in[5];
    const float* b_hh     = (const float*)d_in[6];
    const int*   src      = (const int*)d_in[7];
    const int*   dst      = (const int*)d_in[8];
    const int*   cat      = (const int*)d_in[9];
    const int*   seeds    = (const int*)d_in[10];
    const int*   cand     = (const int*)d_in[11];
    float* out = (float*)d_out;

    float* ws = (float*)d_ws;
    float* emb   = ws; ws += (size_t)N_NODES * DIM;
    float* cst   = ws; ws += (size_t)N_NODES * DIM;
    float* agg   = ws; ws += (size_t)N_NODES * DIM;
    float* cnt   = ws; ws += N_NODES + 16;      // keep 16B alignment
    float* hprev = ws; ws += (size_t)S_SEEDS * DIM;
    float* cnew  = ws; ws += (size_t)S_SEEDS * DIM;
    float* seedh = ws; ws += (size_t)T_STEPS * S_SEEDS * DIM;

    hipMemcpyAsync(emb, node_emb, sizeof(float) * (size_t)N_NODES * DIM,
                   hipMemcpyDeviceToDevice, stream);
    hipMemcpyAsync(cst, cx, sizeof(float) * (size_t)N_NODES * DIM,
                   hipMemcpyDeviceToDevice, stream);

    for (int t = 0; t < T_STEPS; t++) {
        hipMemsetAsync(agg, 0, sizeof(float) * (size_t)N_NODES * DIM, stream);
        hipMemsetAsync(cnt, 0, sizeof(float) * N_NODES, stream);
        agg_kernel<<<(E_EDGES * D4) / 256, 256, 0, stream>>>(
            emb, rel_emb, src + (size_t)t * E_EDGES, dst + (size_t)t * E_EDGES,
            cat + (size_t)t * E_EDGES, agg, cnt);
        gather_seed<<<(S_SEEDS * D4) / 256, 256, 0, stream>>>(
            emb, seeds + (size_t)t * S_SEEDS, hprev);
        norm_add<<<(N_NODES * D4 + 255) / 256, 256, 0, stream>>>(emb, agg, cnt);
        lstm_kernel<<<S_SEEDS / SPB, 512, 0, stream>>>(
            emb, hprev, cst, seeds + (size_t)t * S_SEEDS,
            W_ih, W_hh, b_ih, b_hh,
            seedh + (size_t)t * S_SEEDS * DIM, cnew);
        scatter_seed<<<(S_SEEDS * D4) / 256, 256, 0, stream>>>(
            emb, cst, seeds + (size_t)t * S_SEEDS,
            seedh + (size_t)t * S_SEEDS * DIM, cnew);
    }
    score_kernel<<<T_STEPS * S_SEEDS, 64, 0, stream>>>(seedh, emb, cand, out);
}

// Round 2
// 2433.511 us; speedup vs baseline: 3.4187x; 3.4187x over previous
//
#include <hip/hip_runtime.h>
#include <math.h>

#define N_NODES 150000
#define NODE_STRIDE 150016   // padded per-step stride for CSR arrays
#define DIM 100
#define D4 25                // DIM/4 float4 chunks
#define T_STEPS 16
#define E_EDGES 262144
#define S_SEEDS 4096
#define K_CAND 9
#define SPB 8                // seeds per LSTM block
#define NPB 8                // nodes per fused_agg block (x32 lanes = 256 thr)

__device__ __forceinline__ float sigmoidf_(float x) {
    return 1.0f / (1.0f + __expf(-x));
}

// ============ CSR build (once per call, all 16 steps in parallel) ============

// counts[t][dst] += 1 over all T*E edges
__global__ __launch_bounds__(256) void hist_kernel(
    const int* __restrict__ dst, int* __restrict__ counts) {
    int i = blockIdx.x * blockDim.x + threadIdx.x;   // over T*E
    int t = i / E_EDGES;
    atomicAdd(&counts[(size_t)t * NODE_STRIDE + dst[i]], 1);
}

// one block per step: exclusive scan of counts -> offs (and cursor copy).
// cursor may alias counts (each element is read before being overwritten
// by the same thread).
__global__ __launch_bounds__(256) void scan_kernel(
    const int* counts, int* offs, int* cursor) {
    int t = blockIdx.x;
    const int* cnt = counts + (size_t)t * NODE_STRIDE;
    int* off = offs + (size_t)t * NODE_STRIDE;
    int* cur = cursor + (size_t)t * NODE_STRIDE;
    __shared__ int sums[256];
    int tid = threadIdx.x;
    const int chunk = (N_NODES + 255) / 256;
    int beg = tid * chunk;
    int end = min(beg + chunk, N_NODES);
    int s = 0;
    for (int n = beg; n < end; n++) s += cnt[n];
    sums[tid] = s;
    __syncthreads();
    for (int d = 1; d < 256; d <<= 1) {
        int v = (tid >= d) ? sums[tid - d] : 0;
        __syncthreads();
        sums[tid] += v;
        __syncthreads();
    }
    int run = (tid == 0) ? 0 : sums[tid - 1];
    for (int n = beg; n < end; n++) {
        int c = cnt[n];
        off[n] = run;
        cur[n] = run;
        run += c;
    }
    if (tid == 255) off[N_NODES] = run;   // == E_EDGES
}

// place each edge into its dst bucket; payload packs src (18b) | cat (5b)
__global__ __launch_bounds__(256) void scatter_edges(
    const int* __restrict__ src, const int* __restrict__ dst,
    const int* __restrict__ cat, int* __restrict__ cursor,
    int* __restrict__ sorted) {
    int i = blockIdx.x * blockDim.x + threadIdx.x;   // over T*E
    int t = i / E_EDGES;
    int d = dst[i];
    int pos = atomicAdd(&cursor[(size_t)t * NODE_STRIDE + d], 1);
    sorted[(size_t)t * E_EDGES + pos] = src[i] | (cat[i] << 18);
}

// ============ Per-step fused aggregation + residual (gather, no atomics) ====
// emb_out[n] = emb_in[n] + mean_{e in bucket(n)} emb_in[src_e] * rel[cat_e]
__global__ __launch_bounds__(256) void fused_agg(
    const float* __restrict__ emb_in, float* __restrict__ emb_out,
    const float* __restrict__ rel_emb, const int* __restrict__ offs,
    const int* __restrict__ sorted) {
    int g = threadIdx.x >> 5;
    int lane = threadIdx.x & 31;
    int node = blockIdx.x * NPB + g;
    if (node >= N_NODES) return;
    int beg = offs[node], end = offs[node + 1];
    bool act = lane < D4;
    float4 acc = make_float4(0.f, 0.f, 0.f, 0.f);
    for (int e = beg; e < end; e++) {
        int p = sorted[e];
        int s = p & 0x3FFFF;
        int c = p >> 18;
        if (act) {
            float4 m = ((const float4*)(emb_in + (size_t)s * DIM))[lane];
            float4 r = ((const float4*)(rel_emb + (size_t)c * DIM))[lane];
            acc.x += m.x * r.x; acc.y += m.y * r.y;
            acc.z += m.z * r.z; acc.w += m.w * r.w;
        }
    }
    if (act) {
        float4 b = ((const float4*)(emb_in + (size_t)node * DIM))[lane];
        float inv = (end > beg) ? 1.0f / (float)(end - beg) : 0.0f;
        b.x += acc.x * inv; b.y += acc.y * inv;
        b.z += acc.z * inv; b.w += acc.w * inv;
        ((float4*)(emb_out + (size_t)node * DIM))[lane] = b;
    }
}

// ============ LSTM on seeds (x from emb_new, h_prev from emb_old) ===========
__global__ __launch_bounds__(512) void lstm_kernel(
    const float* __restrict__ emb_new, const float* __restrict__ emb_old,
    const float* __restrict__ c_state, const int* __restrict__ seeds,
    const float* __restrict__ W_ih, const float* __restrict__ W_hh,
    const float* __restrict__ b_ih, const float* __restrict__ b_hh,
    float* __restrict__ h_out, float* __restrict__ c_out) {
    __shared__ float xs[SPB][DIM];
    __shared__ float hs[SPB][DIM];
    __shared__ float gates[SPB][4 * DIM];
    int tid = threadIdx.x;
    int base = blockIdx.x * SPB;

    for (int idx = tid; idx < SPB * DIM; idx += 512) {
        int s = idx / DIM, d = idx - s * DIM;
        int node = seeds[base + s];
        xs[s][d] = emb_new[(size_t)node * DIM + d];
        hs[s][d] = emb_old[(size_t)node * DIM + d];
    }
    __syncthreads();

    if (tid < 4 * DIM) {
        int j = tid;
        float acc[SPB];
#pragma unroll
        for (int s = 0; s < SPB; s++) acc[s] = 0.0f;
        const float* wi = W_ih + (size_t)j * DIM;
        const float* wh = W_hh + (size_t)j * DIM;
        for (int d = 0; d < DIM; d++) {
            float a = wi[d], b = wh[d];
#pragma unroll
            for (int s = 0; s < SPB; s++)
                acc[s] += xs[s][d] * a + hs[s][d] * b;
        }
        float bb = b_ih[j] + b_hh[j];
#pragma unroll
        for (int s = 0; s < SPB; s++) gates[s][j] = acc[s] + bb;
    }
    __syncthreads();

    for (int idx = tid; idx < SPB * DIM; idx += 512) {
        int s = idx / DIM, d = idx - s * DIM;
        int node = seeds[base + s];
        float ig = gates[s][d];
        float fg = gates[s][DIM + d];
        float gg = gates[s][2 * DIM + d];
        float og = gates[s][3 * DIM + d];
        float cp = c_state[(size_t)node * DIM + d];
        float cn = sigmoidf_(fg) * cp + sigmoidf_(ig) * tanhf(gg);
        float hn = sigmoidf_(og) * tanhf(cn);
        h_out[(size_t)(base + s) * DIM + d] = hn;
        c_out[(size_t)(base + s) * DIM + d] = cn;
    }
}

// duplicate seeds write identical values -> benign
__global__ __launch_bounds__(256) void scatter_seed(
    float* __restrict__ emb, float* __restrict__ c_state,
    const int* __restrict__ seeds,
    const float* __restrict__ h_new, const float* __restrict__ c_new) {
    int i = blockIdx.x * blockDim.x + threadIdx.x;  // over S*D4
    int sd = i / D4, q = i - sd * D4;
    int node = seeds[sd];
    ((float4*)(emb + (size_t)node * DIM))[q] = ((const float4*)h_new)[i];
    ((float4*)(c_state + (size_t)node * DIM))[q] = ((const float4*)c_new)[i];
}

// ============ Scoring ============
__global__ __launch_bounds__(64) void score_kernel(
    const float* __restrict__ seed_h, const float* __restrict__ emb,
    const int* __restrict__ cand_idx, float* __restrict__ out) {
    int n = blockIdx.x;
    int lane = threadIdx.x;
    float u0 = seed_h[(size_t)n * DIM + lane];
    float u1 = (lane + 64 < DIM) ? seed_h[(size_t)n * DIM + lane + 64] : 0.0f;
    for (int k = 0; k < K_CAND; k++) {
        int node = cand_idx[n * K_CAND + k];
        const float* ce = emb + (size_t)node * DIM;
        float p = u0 * ce[lane];
        if (lane + 64 < DIM) p += u1 * ce[lane + 64];
        for (int off = 32; off > 0; off >>= 1) p += __shfl_down(p, off);
        if (lane == 0) out[n * K_CAND + k] = p;
    }
}

extern "C" void kernel_launch(void* const* d_in, const int* in_sizes, int n_in,
                              void* d_out, int out_size, void* d_ws, size_t ws_size,
                              hipStream_t stream) {
    const float* node_emb = (const float*)d_in[0];
    const float* cx       = (const float*)d_in[1];
    const float* rel_emb  = (const float*)d_in[2];
    const float* W_ih     = (const float*)d_in[3];
    const float* W_hh     = (const float*)d_in[4];
    const float* b_ih     = (const float*)d_in[5];
    const float* b_hh     = (const float*)d_in[6];
    const int*   src      = (const int*)d_in[7];
    const int*   dst      = (const int*)d_in[8];
    const int*   cat      = (const int*)d_in[9];
    const int*   seeds    = (const int*)d_in[10];
    const int*   cand     = (const int*)d_in[11];
    float* out = (float*)d_out;

    float* ws = (float*)d_ws;
    float* emb_a = ws; ws += (size_t)N_NODES * DIM;
    float* emb_b = ws; ws += (size_t)N_NODES * DIM;
    float* cst   = ws; ws += (size_t)N_NODES * DIM;
    float* cnew  = ws; ws += (size_t)S_SEEDS * DIM;
    float* seedh = ws; ws += (size_t)T_STEPS * S_SEEDS * DIM;
    int* counts  = (int*)ws; ws += (size_t)T_STEPS * NODE_STRIDE;  // also cursor
    int* offs    = (int*)ws; ws += (size_t)T_STEPS * NODE_STRIDE;
    int* sorted  = (int*)ws; ws += (size_t)T_STEPS * E_EDGES;

    hipMemcpyAsync(emb_a, node_emb, sizeof(float) * (size_t)N_NODES * DIM,
                   hipMemcpyDeviceToDevice, stream);
    hipMemcpyAsync(cst, cx, sizeof(float) * (size_t)N_NODES * DIM,
                   hipMemcpyDeviceToDevice, stream);

    // ---- CSR build for all 16 steps ----
    hipMemsetAsync(counts, 0, sizeof(int) * (size_t)T_STEPS * NODE_STRIDE, stream);
    hist_kernel<<<(T_STEPS * E_EDGES) / 256, 256, 0, stream>>>(dst, counts);
    scan_kernel<<<T_STEPS, 256, 0, stream>>>(counts, offs, counts /*cursor*/);
    scatter_edges<<<(T_STEPS * E_EDGES) / 256, 256, 0, stream>>>(
        src, dst, cat, counts /*cursor*/, sorted);

    float* cur = emb_a;
    float* nxt = emb_b;
    for (int t = 0; t < T_STEPS; t++) {
        fused_agg<<<(N_NODES + NPB - 1) / NPB, 256, 0, stream>>>(
            cur, nxt, rel_emb,
            offs + (size_t)t * NODE_STRIDE, sorted + (size_t)t * E_EDGES);
        lstm_kernel<<<S_SEEDS / SPB, 512, 0, stream>>>(
            nxt, cur, cst, seeds + (size_t)t * S_SEEDS,
            W_ih, W_hh, b_ih, b_hh,
            seedh + (size_t)t * S_SEEDS * DIM, cnew);
        scatter_seed<<<(S_SEEDS * D4) / 256, 256, 0, stream>>>(
            nxt, cst, seeds + (size_t)t * S_SEEDS,
            seedh + (size_t)t * S_SEEDS * DIM, cnew);
        float* tmp = cur; cur = nxt; nxt = tmp;
    }
    score_kernel<<<T_STEPS * S_SEEDS, 64, 0, stream>>>(seedh, cur, cand, out);
}

// Round 3
// 2103.415 us; speedup vs baseline: 3.9552x; 1.1569x over previous
//
#include <hip/hip_runtime.h>
#include <math.h>

#define N_NODES 150000
#define NODE_STRIDE 150016   // padded per-step stride for CSR arrays
#define DIM 100
#define D4 25                // DIM/4 float4 chunks
#define T_STEPS 16
#define E_EDGES 262144
#define S_SEEDS 4096
#define K_CAND 9
#define SPB 8                // seeds per LSTM block
#define NPB 8                // nodes per fused_agg block (x32 lanes = 256 thr)

#define SCAN_CHUNK 1024
#define SCAN_NBLK ((N_NODES + SCAN_CHUNK - 1) / SCAN_CHUNK)   // 147

__device__ __forceinline__ float sigmoidf_(float x) {
    return 1.0f / (1.0f + __expf(-x));
}

// ============ CSR build (once per call, all 16 steps in parallel) ============

// counts[t][dst] += 1 over all T*E edges
__global__ __launch_bounds__(256) void hist_kernel(
    const int* __restrict__ dst, int* __restrict__ counts) {
    int i = blockIdx.x * blockDim.x + threadIdx.x;   // over T*E
    int t = i / E_EDGES;
    atomicAdd(&counts[(size_t)t * NODE_STRIDE + dst[i]], 1);
}

// ---- 3-phase multi-block exclusive scan of counts -> offs (+cursor copy) ----
// Phase A: per-1024-chunk sums
__global__ __launch_bounds__(256) void scan_partial(
    const int* __restrict__ counts, int* __restrict__ blocksums) {
    int t = blockIdx.x / SCAN_NBLK;
    int b = blockIdx.x % SCAN_NBLK;
    const int* cnt = counts + (size_t)t * NODE_STRIDE;
    int base = b * SCAN_CHUNK;
    int tid = threadIdx.x;
    int s = 0;
#pragma unroll
    for (int k = 0; k < 4; k++) {
        int n = base + tid * 4 + k;
        if (n < N_NODES) s += cnt[n];
    }
    __shared__ int red[256];
    red[tid] = s;
    __syncthreads();
    for (int d = 128; d > 0; d >>= 1) {
        if (tid < d) red[tid] += red[tid + d];
        __syncthreads();
    }
    if (tid == 0) blocksums[t * SCAN_NBLK + b] = red[0];
}

// Phase B: exclusive scan of the 147 block sums per step
__global__ __launch_bounds__(256) void scan_blocksums(
    int* __restrict__ blocksums, int* __restrict__ offs) {
    int t = blockIdx.x;
    int tid = threadIdx.x;
    __shared__ int sh[256];
    sh[tid] = (tid < SCAN_NBLK) ? blocksums[t * SCAN_NBLK + tid] : 0;
    __syncthreads();
    for (int d = 1; d < 256; d <<= 1) {
        int v = (tid >= d) ? sh[tid - d] : 0;
        __syncthreads();
        sh[tid] += v;
        __syncthreads();
    }
    // write back exclusive prefix
    if (tid < SCAN_NBLK)
        blocksums[t * SCAN_NBLK + tid] = (tid == 0) ? 0 : sh[tid - 1];
    if (tid == 0) offs[(size_t)t * NODE_STRIDE + N_NODES] = E_EDGES;
}

// Phase C: local exclusive scan of each chunk + base, write offs & cursor
__global__ __launch_bounds__(256) void scan_apply(
    const int* __restrict__ counts, const int* __restrict__ blocksums,
    int* __restrict__ offs, int* __restrict__ cursor) {
    int t = blockIdx.x / SCAN_NBLK;
    int b = blockIdx.x % SCAN_NBLK;
    const int* cnt = counts + (size_t)t * NODE_STRIDE;
    int* off = offs + (size_t)t * NODE_STRIDE;
    int* cur = cursor + (size_t)t * NODE_STRIDE;
    int base = b * SCAN_CHUNK;
    int tid = threadIdx.x;

    int v[4];
    int s = 0;
#pragma unroll
    for (int k = 0; k < 4; k++) {
        int n = base + tid * 4 + k;
        v[k] = (n < N_NODES) ? cnt[n] : 0;
        s += v[k];
    }
    __shared__ int sh[256];
    sh[tid] = s;
    __syncthreads();
    for (int d = 1; d < 256; d <<= 1) {
        int x = (tid >= d) ? sh[tid - d] : 0;
        __syncthreads();
        sh[tid] += x;
        __syncthreads();
    }
    int run = blocksums[t * SCAN_NBLK + b] + ((tid == 0) ? 0 : sh[tid - 1]);
#pragma unroll
    for (int k = 0; k < 4; k++) {
        int n = base + tid * 4 + k;
        if (n < N_NODES) {
            off[n] = run;
            cur[n] = run;
            run += v[k];
        }
    }
}

// place each edge into its dst bucket; payload packs src (18b) | cat (5b)
__global__ __launch_bounds__(256) void scatter_edges(
    const int* __restrict__ src, const int* __restrict__ dst,
    const int* __restrict__ cat, int* __restrict__ cursor,
    int* __restrict__ sorted) {
    int i = blockIdx.x * blockDim.x + threadIdx.x;   // over T*E
    int t = i / E_EDGES;
    int d = dst[i];
    int pos = atomicAdd(&cursor[(size_t)t * NODE_STRIDE + d], 1);
    sorted[(size_t)t * E_EDGES + pos] = src[i] | (cat[i] << 18);
}

// ============ Per-step fused aggregation + residual (gather, no atomics) ====
// emb_out[n] = emb_in[n] + mean_{e in bucket(n)} emb_in[src_e] * rel[cat_e]
__global__ __launch_bounds__(256) void fused_agg(
    const float* __restrict__ emb_in, float* __restrict__ emb_out,
    const float* __restrict__ rel_emb, const int* __restrict__ offs,
    const int* __restrict__ sorted) {
    int g = threadIdx.x >> 5;
    int lane = threadIdx.x & 31;
    int node = blockIdx.x * NPB + g;
    if (node >= N_NODES) return;
    int beg = offs[node], end = offs[node + 1];
    bool act = lane < D4;
    float4 acc = make_float4(0.f, 0.f, 0.f, 0.f);
    for (int e = beg; e < end; e++) {
        int p = sorted[e];
        int s = p & 0x3FFFF;
        int c = p >> 18;
        if (act) {
            float4 m = ((const float4*)(emb_in + (size_t)s * DIM))[lane];
            float4 r = ((const float4*)(rel_emb + (size_t)c * DIM))[lane];
            acc.x += m.x * r.x; acc.y += m.y * r.y;
            acc.z += m.z * r.z; acc.w += m.w * r.w;
        }
    }
    if (act) {
        float4 b = ((const float4*)(emb_in + (size_t)node * DIM))[lane];
        float inv = (end > beg) ? 1.0f / (float)(end - beg) : 0.0f;
        b.x += acc.x * inv; b.y += acc.y * inv;
        b.z += acc.z * inv; b.w += acc.w * inv;
        ((float4*)(emb_out + (size_t)node * DIM))[lane] = b;
    }
}

// ============ LSTM on seeds (x from emb_new, h_prev from emb_old) ===========
__global__ __launch_bounds__(512) void lstm_kernel(
    const float* __restrict__ emb_new, const float* __restrict__ emb_old,
    const float* __restrict__ c_state, const int* __restrict__ seeds,
    const float* __restrict__ W_ih, const float* __restrict__ W_hh,
    const float* __restrict__ b_ih, const float* __restrict__ b_hh,
    float* __restrict__ h_out, float* __restrict__ c_out) {
    __shared__ float xs[SPB][DIM];
    __shared__ float hs[SPB][DIM];
    __shared__ float gates[SPB][4 * DIM];
    int tid = threadIdx.x;
    int base = blockIdx.x * SPB;

    for (int idx = tid; idx < SPB * DIM; idx += 512) {
        int s = idx / DIM, d = idx - s * DIM;
        int node = seeds[base + s];
        xs[s][d] = emb_new[(size_t)node * DIM + d];
        hs[s][d] = emb_old[(size_t)node * DIM + d];
    }
    __syncthreads();

    if (tid < 4 * DIM) {
        int j = tid;
        float acc[SPB];
#pragma unroll
        for (int s = 0; s < SPB; s++) acc[s] = 0.0f;
        const float* wi = W_ih + (size_t)j * DIM;
        const float* wh = W_hh + (size_t)j * DIM;
        for (int d = 0; d < DIM; d++) {
            float a = wi[d], b = wh[d];
#pragma unroll
            for (int s = 0; s < SPB; s++)
                acc[s] += xs[s][d] * a + hs[s][d] * b;
        }
        float bb = b_ih[j] + b_hh[j];
#pragma unroll
        for (int s = 0; s < SPB; s++) gates[s][j] = acc[s] + bb;
    }
    __syncthreads();

    for (int idx = tid; idx < SPB * DIM; idx += 512) {
        int s = idx / DIM, d = idx - s * DIM;
        int node = seeds[base + s];
        float ig = gates[s][d];
        float fg = gates[s][DIM + d];
        float gg = gates[s][2 * DIM + d];
        float og = gates[s][3 * DIM + d];
        float cp = c_state[(size_t)node * DIM + d];
        float cn = sigmoidf_(fg) * cp + sigmoidf_(ig) * tanhf(gg);
        float hn = sigmoidf_(og) * tanhf(cn);
        h_out[(size_t)(base + s) * DIM + d] = hn;
        c_out[(size_t)(base + s) * DIM + d] = cn;
    }
}

// duplicate seeds write identical values -> benign
__global__ __launch_bounds__(256) void scatter_seed(
    float* __restrict__ emb, float* __restrict__ c_state,
    const int* __restrict__ seeds,
    const float* __restrict__ h_new, const float* __restrict__ c_new) {
    int i = blockIdx.x * blockDim.x + threadIdx.x;  // over S*D4
    int sd = i / D4, q = i - sd * D4;
    int node = seeds[sd];
    ((float4*)(emb + (size_t)node * DIM))[q] = ((const float4*)h_new)[i];
    ((float4*)(c_state + (size_t)node * DIM))[q] = ((const float4*)c_new)[i];
}

// ============ Scoring ============
__global__ __launch_bounds__(64) void score_kernel(
    const float* __restrict__ seed_h, const float* __restrict__ emb,
    const int* __restrict__ cand_idx, float* __restrict__ out) {
    int n = blockIdx.x;
    int lane = threadIdx.x;
    float u0 = seed_h[(size_t)n * DIM + lane];
    float u1 = (lane + 64 < DIM) ? seed_h[(size_t)n * DIM + lane + 64] : 0.0f;
    for (int k = 0; k < K_CAND; k++) {
        int node = cand_idx[n * K_CAND + k];
        const float* ce = emb + (size_t)node * DIM;
        float p = u0 * ce[lane];
        if (lane + 64 < DIM) p += u1 * ce[lane + 64];
        for (int off = 32; off > 0; off >>= 1) p += __shfl_down(p, off);
        if (lane == 0) out[n * K_CAND + k] = p;
    }
}

extern "C" void kernel_launch(void* const* d_in, const int* in_sizes, int n_in,
                              void* d_out, int out_size, void* d_ws, size_t ws_size,
                              hipStream_t stream) {
    const float* node_emb = (const float*)d_in[0];
    const float* cx       = (const float*)d_in[1];
    const float* rel_emb  = (const float*)d_in[2];
    const float* W_ih     = (const float*)d_in[3];
    const float* W_hh     = (const float*)d_in[4];
    const float* b_ih     = (const float*)d_in[5];
    const float* b_hh     = (const float*)d_in[6];
    const int*   src      = (const int*)d_in[7];
    const int*   dst      = (const int*)d_in[8];
    const int*   cat      = (const int*)d_in[9];
    const int*   seeds    = (const int*)d_in[10];
    const int*   cand     = (const int*)d_in[11];
    float* out = (float*)d_out;

    float* ws = (float*)d_ws;
    float* emb_a = ws; ws += (size_t)N_NODES * DIM;
    float* emb_b = ws; ws += (size_t)N_NODES * DIM;
    float* cst   = ws; ws += (size_t)N_NODES * DIM;
    float* cnew  = ws; ws += (size_t)S_SEEDS * DIM;
    float* seedh = ws; ws += (size_t)T_STEPS * S_SEEDS * DIM;
    int* counts  = (int*)ws; ws += (size_t)T_STEPS * NODE_STRIDE;  // also cursor
    int* offs    = (int*)ws; ws += (size_t)T_STEPS * NODE_STRIDE;
    int* sorted  = (int*)ws; ws += (size_t)T_STEPS * E_EDGES;
    int* bsums   = (int*)ws; ws += (size_t)T_STEPS * SCAN_NBLK;

    hipMemcpyAsync(emb_a, node_emb, sizeof(float) * (size_t)N_NODES * DIM,
                   hipMemcpyDeviceToDevice, stream);
    hipMemcpyAsync(cst, cx, sizeof(float) * (size_t)N_NODES * DIM,
                   hipMemcpyDeviceToDevice, stream);

    // ---- CSR build for all 16 steps ----
    hipMemsetAsync(counts, 0, sizeof(int) * (size_t)T_STEPS * NODE_STRIDE, stream);
    hist_kernel<<<(T_STEPS * E_EDGES) / 256, 256, 0, stream>>>(dst, counts);
    scan_partial<<<T_STEPS * SCAN_NBLK, 256, 0, stream>>>(counts, bsums);
    scan_blocksums<<<T_STEPS, 256, 0, stream>>>(bsums, offs);
    scan_apply<<<T_STEPS * SCAN_NBLK, 256, 0, stream>>>(
        counts, bsums, offs, counts /*cursor aliases counts*/);
    scatter_edges<<<(T_STEPS * E_EDGES) / 256, 256, 0, stream>>>(
        src, dst, cat, counts /*cursor*/, sorted);

    float* cur = emb_a;
    float* nxt = emb_b;
    for (int t = 0; t < T_STEPS; t++) {
        fused_agg<<<(N_NODES + NPB - 1) / NPB, 256, 0, stream>>>(
            cur, nxt, rel_emb,
            offs + (size_t)t * NODE_STRIDE, sorted + (size_t)t * E_EDGES);
        lstm_kernel<<<S_SEEDS / SPB, 512, 0, stream>>>(
            nxt, cur, cst, seeds + (size_t)t * S_SEEDS,
            W_ih, W_hh, b_ih, b_hh,
            seedh + (size_t)t * S_SEEDS * DIM, cnew);
        scatter_seed<<<(S_SEEDS * D4) / 256, 256, 0, stream>>>(
            nxt, cst, seeds + (size_t)t * S_SEEDS,
            seedh + (size_t)t * S_SEEDS * DIM, cnew);
        float* tmp = cur; cur = nxt; nxt = tmp;
    }
    score_kernel<<<T_STEPS * S_SEEDS, 64, 0, stream>>>(seedh, cur, cand, out);
}

// Round 4
// 1843.244 us; speedup vs baseline: 4.5135x; 1.1411x over previous
//
#include <hip/hip_runtime.h>
#include <math.h>

#define N_NODES 150000
#define NODE_STRIDE 150016   // padded per-step stride for offs array
#define DIM 100
#define D4 25                // DIM/4 float4 chunks
#define T_STEPS 16
#define E_EDGES 262144
#define S_SEEDS 4096
#define K_CAND 9
#define SPB 8                // seeds per LSTM block
#define NPB 8                // nodes per fused_agg block (x32 lanes = 256 thr)

#define CB 32                // coarse buckets per step
#define BSPAN 4688           // nodes per coarse bucket; 32*4688 = 150016 >= N

__device__ __forceinline__ float sigmoidf_(float x) {
    return 1.0f / (1.0f + __expf(-x));
}

// ============ CSR build: hierarchical two-level counting sort ============

// Pass 1: coarse histogram (LDS-aggregated)
__global__ __launch_bounds__(256) void coarse_hist(
    const int* __restrict__ dst, int* __restrict__ ccnt) {
    int t = blockIdx.x >> 10;                       // 1024 blocks per step
    int i = blockIdx.x * 256 + threadIdx.x;         // global edge index
    __shared__ int h[CB];
    if (threadIdx.x < CB) h[threadIdx.x] = 0;
    __syncthreads();
    int d = dst[i];
    atomicAdd(&h[d / BSPAN], 1);
    __syncthreads();
    if (threadIdx.x < CB)
        atomicAdd(&ccnt[t * CB + threadIdx.x], h[threadIdx.x]);
}

// Pass 2: per-step exclusive scan of 32 coarse counts
__global__ __launch_bounds__(64) void coarse_scan(
    const int* __restrict__ ccnt, int* __restrict__ coffs,
    int* __restrict__ ccur) {
    int t = blockIdx.x;
    int tid = threadIdx.x;
    __shared__ int sh[CB];
    if (tid < CB) sh[tid] = ccnt[t * CB + tid];
    __syncthreads();
    if (tid == 0) {
        int run = 0;
        for (int b = 0; b < CB; b++) { int c = sh[b]; sh[b] = run; run += c; }
    }
    __syncthreads();
    if (tid < CB) {
        coffs[t * (CB + 1) + tid] = sh[tid];
        ccur[t * CB + tid] = sh[tid];
    }
    if (tid == 0) coffs[t * (CB + 1) + CB] = E_EDGES;
}

// Pass 3: block-multisplit coarse scatter -> int2{src|cat<<18, dst} entries
__global__ __launch_bounds__(256) void coarse_scatter(
    const int* __restrict__ src, const int* __restrict__ dst,
    const int* __restrict__ cat, int* __restrict__ ccur,
    int2* __restrict__ cbuf) {
    int t = blockIdx.x >> 10;
    int i = blockIdx.x * 256 + threadIdx.x;
    __shared__ int h[CB];
    __shared__ int base[CB];
    if (threadIdx.x < CB) h[threadIdx.x] = 0;
    __syncthreads();
    int d = dst[i];
    int b = d / BSPAN;
    int rank = atomicAdd(&h[b], 1);
    __syncthreads();
    if (threadIdx.x < CB && h[threadIdx.x] > 0)
        base[threadIdx.x] = atomicAdd(&ccur[t * CB + threadIdx.x], h[threadIdx.x]);
    __syncthreads();
    int2 entry;
    entry.x = src[i] | (cat[i] << 18);
    entry.y = d;
    cbuf[(size_t)t * E_EDGES + base[b] + rank] = entry;
}

// Pass 4: per (step,bucket) fine sort in LDS; writes global offs AND sorted
__global__ __launch_bounds__(256) void fine_build(
    const int2* __restrict__ cbuf, const int* __restrict__ coffs,
    int* __restrict__ offs, int* __restrict__ sorted) {
    int t = blockIdx.x >> 5;
    int b = blockIdx.x & 31;
    int node0 = b * BSPAN;
    int nodes = min(BSPAN, N_NODES - node0);
    int ebeg = coffs[t * (CB + 1) + b];
    int eend = coffs[t * (CB + 1) + b + 1];
    const int2* ebuf = cbuf + (size_t)t * E_EDGES;
    int* off = offs + (size_t)t * NODE_STRIDE;
    int* srt = sorted + (size_t)t * E_EDGES;
    __shared__ int cnt[BSPAN];
    __shared__ int sums[256];
    int tid = threadIdx.x;

    for (int j = tid; j < BSPAN; j += 256) cnt[j] = 0;
    __syncthreads();
    for (int e = ebeg + tid; e < eend; e += 256)
        atomicAdd(&cnt[ebuf[e].y - node0], 1);
    __syncthreads();

    // chunked exclusive scan over BSPAN elements
    const int chunk = (BSPAN + 255) / 256;   // 19
    int cbeg = tid * chunk;
    int cend = min(cbeg + chunk, BSPAN);
    int s = 0;
    for (int j = cbeg; j < cend; j++) s += cnt[j];
    sums[tid] = s;
    __syncthreads();
    for (int d = 1; d < 256; d <<= 1) {
        int v = (tid >= d) ? sums[tid - d] : 0;
        __syncthreads();
        sums[tid] += v;
        __syncthreads();
    }
    int run = (tid == 0) ? 0 : sums[tid - 1];
    for (int j = cbeg; j < cend; j++) {
        int c = cnt[j];
        cnt[j] = run;                         // local exclusive offset = cursor
        if (j < nodes) off[node0 + j] = ebeg + run;
        run += c;
    }
    if (tid == 0 && b == CB - 1) off[N_NODES] = E_EDGES;
    __syncthreads();

    for (int e = ebeg + tid; e < eend; e += 256) {
        int2 en = ebuf[e];
        int pos = atomicAdd(&cnt[en.y - node0], 1);
        srt[ebeg + pos] = en.x;
    }
}

// ============ Per-step fused aggregation + residual (gather, no atomics) ====
// emb_out[n] = emb_in[n] + mean_{e in bucket(n)} emb_in[src_e] * rel[cat_e]
__global__ __launch_bounds__(256) void fused_agg(
    const float* __restrict__ emb_in, float* __restrict__ emb_out,
    const float* __restrict__ rel_emb, const int* __restrict__ offs,
    const int* __restrict__ sorted) {
    int g = threadIdx.x >> 5;
    int lane = threadIdx.x & 31;
    int node = blockIdx.x * NPB + g;
    if (node >= N_NODES) return;
    int beg = offs[node], end = offs[node + 1];
    bool act = lane < D4;
    float4 acc = make_float4(0.f, 0.f, 0.f, 0.f);
    int e = beg;
    for (; e + 1 < end; e += 2) {          // 2 independent gathers in flight
        int p0 = sorted[e], p1 = sorted[e + 1];
        int s0 = p0 & 0x3FFFF, c0 = p0 >> 18;
        int s1 = p1 & 0x3FFFF, c1 = p1 >> 18;
        if (act) {
            float4 m0 = ((const float4*)(emb_in + (size_t)s0 * DIM))[lane];
            float4 r0 = ((const float4*)(rel_emb + (size_t)c0 * DIM))[lane];
            float4 m1 = ((const float4*)(emb_in + (size_t)s1 * DIM))[lane];
            float4 r1 = ((const float4*)(rel_emb + (size_t)c1 * DIM))[lane];
            acc.x += m0.x * r0.x; acc.y += m0.y * r0.y;
            acc.z += m0.z * r0.z; acc.w += m0.w * r0.w;
            acc.x += m1.x * r1.x; acc.y += m1.y * r1.y;
            acc.z += m1.z * r1.z; acc.w += m1.w * r1.w;
        }
    }
    if (e < end) {
        int p = sorted[e];
        int s = p & 0x3FFFF, c = p >> 18;
        if (act) {
            float4 m = ((const float4*)(emb_in + (size_t)s * DIM))[lane];
            float4 r = ((const float4*)(rel_emb + (size_t)c * DIM))[lane];
            acc.x += m.x * r.x; acc.y += m.y * r.y;
            acc.z += m.z * r.z; acc.w += m.w * r.w;
        }
    }
    if (act) {
        float4 bv = ((const float4*)(emb_in + (size_t)node * DIM))[lane];
        float inv = (end > beg) ? 1.0f / (float)(end - beg) : 0.0f;
        bv.x += acc.x * inv; bv.y += acc.y * inv;
        bv.z += acc.z * inv; bv.w += acc.w * inv;
        ((float4*)(emb_out + (size_t)node * DIM))[lane] = bv;
    }
}

// ============ LSTM on seeds (x from emb_new, h_prev from emb_old) ===========
__global__ __launch_bounds__(512) void lstm_kernel(
    const float* __restrict__ emb_new, const float* __restrict__ emb_old,
    const float* __restrict__ c_state, const int* __restrict__ seeds,
    const float* __restrict__ W_ih, const float* __restrict__ W_hh,
    const float* __restrict__ b_ih, const float* __restrict__ b_hh,
    float* __restrict__ h_out, float* __restrict__ c_out) {
    __shared__ float xs[SPB][DIM];
    __shared__ float hs[SPB][DIM];
    __shared__ float gates[SPB][4 * DIM];
    int tid = threadIdx.x;
    int base = blockIdx.x * SPB;

    for (int idx = tid; idx < SPB * DIM; idx += 512) {
        int s = idx / DIM, d = idx - s * DIM;
        int node = seeds[base + s];
        xs[s][d] = emb_new[(size_t)node * DIM + d];
        hs[s][d] = emb_old[(size_t)node * DIM + d];
    }
    __syncthreads();

    if (tid < 4 * DIM) {
        int j = tid;
        float acc[SPB];
#pragma unroll
        for (int s = 0; s < SPB; s++) acc[s] = 0.0f;
        const float* wi = W_ih + (size_t)j * DIM;
        const float* wh = W_hh + (size_t)j * DIM;
        for (int d = 0; d < DIM; d++) {
            float a = wi[d], b = wh[d];
#pragma unroll
            for (int s = 0; s < SPB; s++)
                acc[s] += xs[s][d] * a + hs[s][d] * b;
        }
        float bb = b_ih[j] + b_hh[j];
#pragma unroll
        for (int s = 0; s < SPB; s++) gates[s][j] = acc[s] + bb;
    }
    __syncthreads();

    for (int idx = tid; idx < SPB * DIM; idx += 512) {
        int s = idx / DIM, d = idx - s * DIM;
        int node = seeds[base + s];
        float ig = gates[s][d];
        float fg = gates[s][DIM + d];
        float gg = gates[s][2 * DIM + d];
        float og = gates[s][3 * DIM + d];
        float cp = c_state[(size_t)node * DIM + d];
        float cn = sigmoidf_(fg) * cp + sigmoidf_(ig) * tanhf(gg);
        float hn = sigmoidf_(og) * tanhf(cn);
        h_out[(size_t)(base + s) * DIM + d] = hn;
        c_out[(size_t)(base + s) * DIM + d] = cn;
    }
}

// duplicate seeds write identical values -> benign
__global__ __launch_bounds__(256) void scatter_seed(
    float* __restrict__ emb, float* __restrict__ c_state,
    const int* __restrict__ seeds,
    const float* __restrict__ h_new, const float* __restrict__ c_new) {
    int i = blockIdx.x * blockDim.x + threadIdx.x;  // over S*D4
    int sd = i / D4, q = i - sd * D4;
    int node = seeds[sd];
    ((float4*)(emb + (size_t)node * DIM))[q] = ((const float4*)h_new)[i];
    ((float4*)(c_state + (size_t)node * DIM))[q] = ((const float4*)c_new)[i];
}

// ============ Scoring ============
__global__ __launch_bounds__(64) void score_kernel(
    const float* __restrict__ seed_h, const float* __restrict__ emb,
    const int* __restrict__ cand_idx, float* __restrict__ out) {
    int n = blockIdx.x;
    int lane = threadIdx.x;
    float u0 = seed_h[(size_t)n * DIM + lane];
    float u1 = (lane + 64 < DIM) ? seed_h[(size_t)n * DIM + lane + 64] : 0.0f;
    for (int k = 0; k < K_CAND; k++) {
        int node = cand_idx[n * K_CAND + k];
        const float* ce = emb + (size_t)node * DIM;
        float p = u0 * ce[lane];
        if (lane + 64 < DIM) p += u1 * ce[lane + 64];
        for (int off = 32; off > 0; off >>= 1) p += __shfl_down(p, off);
        if (lane == 0) out[n * K_CAND + k] = p;
    }
}

extern "C" void kernel_launch(void* const* d_in, const int* in_sizes, int n_in,
                              void* d_out, int out_size, void* d_ws, size_t ws_size,
                              hipStream_t stream) {
    const float* node_emb = (const float*)d_in[0];
    const float* cx       = (const float*)d_in[1];
    const float* rel_emb  = (const float*)d_in[2];
    const float* W_ih     = (const float*)d_in[3];
    const float* W_hh     = (const float*)d_in[4];
    const float* b_ih     = (const float*)d_in[5];
    const float* b_hh     = (const float*)d_in[6];
    const int*   src      = (const int*)d_in[7];
    const int*   dst      = (const int*)d_in[8];
    const int*   cat      = (const int*)d_in[9];
    const int*   seeds    = (const int*)d_in[10];
    const int*   cand     = (const int*)d_in[11];
    float* out = (float*)d_out;

    float* ws = (float*)d_ws;
    float* emb_a = ws; ws += (size_t)N_NODES * DIM;
    float* emb_b = ws; ws += (size_t)N_NODES * DIM;
    float* cst   = ws; ws += (size_t)N_NODES * DIM;
    float* cnew  = ws; ws += (size_t)S_SEEDS * DIM;
    float* seedh = ws; ws += (size_t)T_STEPS * S_SEEDS * DIM;
    int* offs    = (int*)ws; ws += (size_t)T_STEPS * NODE_STRIDE;
    int* sorted  = (int*)ws; ws += (size_t)T_STEPS * E_EDGES;
    int* ccnt    = (int*)ws; ws += T_STEPS * CB;
    int* ccur    = (int*)ws; ws += T_STEPS * CB;
    int* coffs   = (int*)ws; ws += T_STEPS * (CB + 1);
    // coarse entry buffer (33.6 MB) aliases emb_b: dead until first fused_agg
    int2* cbuf = (int2*)emb_b;

    // ---- CSR build for all 16 steps (two-level counting sort) ----
    hipMemsetAsync(ccnt, 0, sizeof(int) * T_STEPS * CB, stream);
    coarse_hist<<<T_STEPS * 1024, 256, 0, stream>>>(dst, ccnt);
    coarse_scan<<<T_STEPS, 64, 0, stream>>>(ccnt, coffs, ccur);
    coarse_scatter<<<T_STEPS * 1024, 256, 0, stream>>>(src, dst, cat, ccur, cbuf);
    fine_build<<<T_STEPS * CB, 256, 0, stream>>>(cbuf, coffs, offs, sorted);

    hipMemcpyAsync(emb_a, node_emb, sizeof(float) * (size_t)N_NODES * DIM,
                   hipMemcpyDeviceToDevice, stream);
    hipMemcpyAsync(cst, cx, sizeof(float) * (size_t)N_NODES * DIM,
                   hipMemcpyDeviceToDevice, stream);

    float* cur = emb_a;
    float* nxt = emb_b;
    for (int t = 0; t < T_STEPS; t++) {
        fused_agg<<<(N_NODES + NPB - 1) / NPB, 256, 0, stream>>>(
            cur, nxt, rel_emb,
            offs + (size_t)t * NODE_STRIDE, sorted + (size_t)t * E_EDGES);
        lstm_kernel<<<S_SEEDS / SPB, 512, 0, stream>>>(
            nxt, cur, cst, seeds + (size_t)t * S_SEEDS,
            W_ih, W_hh, b_ih, b_hh,
            seedh + (size_t)t * S_SEEDS * DIM, cnew);
        scatter_seed<<<(S_SEEDS * D4) / 256, 256, 0, stream>>>(
            nxt, cst, seeds + (size_t)t * S_SEEDS,
            seedh + (size_t)t * S_SEEDS * DIM, cnew);
        float* tmp = cur; cur = nxt; nxt = tmp;
    }
    score_kernel<<<T_STEPS * S_SEEDS, 64, 0, stream>>>(seedh, cur, cand, out);
}

// Round 6
// 1690.378 us; speedup vs baseline: 4.9217x; 1.0904x over previous
//
#include <hip/hip_runtime.h>
#include <math.h>

#define N_NODES 150000
#define NODE_STRIDE 150016   // padded per-step stride for offs/meta arrays
#define DIM 100
#define D4 25                // DIM/4 float4 chunks
#define T_STEPS 16
#define E_EDGES 262144
#define S_SEEDS 4096
#define K_CAND 9
#define SPB 16               // seeds per LSTM block
#define NPB 8                // nodes per fused_agg block (8 groups x 32 lanes)

#define CB 32                // coarse buckets per step
#define BSPAN 4688           // nodes per coarse bucket; 32*4688 = 150016 >= N

__device__ __forceinline__ float sigmoidf_(float x) {
    return 1.0f / (1.0f + __expf(-x));
}

// ============ CSR build: hierarchical two-level counting sort ============

__global__ __launch_bounds__(256) void coarse_hist(
    const int* __restrict__ dst, int* __restrict__ ccnt) {
    int t = blockIdx.x >> 10;
    int i = blockIdx.x * 256 + threadIdx.x;
    __shared__ int h[CB];
    if (threadIdx.x < CB) h[threadIdx.x] = 0;
    __syncthreads();
    int d = dst[i];
    atomicAdd(&h[d / BSPAN], 1);
    __syncthreads();
    if (threadIdx.x < CB)
        atomicAdd(&ccnt[t * CB + threadIdx.x], h[threadIdx.x]);
}

__global__ __launch_bounds__(64) void coarse_scan(
    const int* __restrict__ ccnt, int* __restrict__ coffs,
    int* __restrict__ ccur) {
    int t = blockIdx.x;
    int tid = threadIdx.x;
    __shared__ int sh[CB];
    if (tid < CB) sh[tid] = ccnt[t * CB + tid];
    __syncthreads();
    if (tid == 0) {
        int run = 0;
        for (int b = 0; b < CB; b++) { int c = sh[b]; sh[b] = run; run += c; }
    }
    __syncthreads();
    if (tid < CB) {
        coffs[t * (CB + 1) + tid] = sh[tid];
        ccur[t * CB + tid] = sh[tid];
    }
    if (tid == 0) coffs[t * (CB + 1) + CB] = E_EDGES;
}

__global__ __launch_bounds__(256) void coarse_scatter(
    const int* __restrict__ src, const int* __restrict__ dst,
    const int* __restrict__ cat, int* __restrict__ ccur,
    int2* __restrict__ cbuf) {
    int t = blockIdx.x >> 10;
    int i = blockIdx.x * 256 + threadIdx.x;
    __shared__ int h[CB];
    __shared__ int base[CB];
    if (threadIdx.x < CB) h[threadIdx.x] = 0;
    __syncthreads();
    int d = dst[i];
    int b = d / BSPAN;
    int rank = atomicAdd(&h[b], 1);
    __syncthreads();
    if (threadIdx.x < CB && h[threadIdx.x] > 0)
        base[threadIdx.x] = atomicAdd(&ccur[t * CB + threadIdx.x], h[threadIdx.x]);
    __syncthreads();
    int2 entry;
    entry.x = src[i] | (cat[i] << 18);
    entry.y = d;
    cbuf[(size_t)t * E_EDGES + base[b] + rank] = entry;
}

// Per (step,bucket): fine counting sort in LDS; emits sorted[], and per-node
// meta = {deg, global_beg, payload0, payload1} (fast path for deg<=2).
__global__ __launch_bounds__(256) void fine_build(
    const int2* __restrict__ cbuf, const int* __restrict__ coffs,
    int4* __restrict__ meta, int* __restrict__ sorted) {
    int t = blockIdx.x >> 5;
    int b = blockIdx.x & 31;
    int node0 = b * BSPAN;
    int nodes = min(BSPAN, N_NODES - node0);
    int ebeg = coffs[t * (CB + 1) + b];
    int eend = coffs[t * (CB + 1) + b + 1];
    const int2* ebuf = cbuf + (size_t)t * E_EDGES;
    int4* mt = meta + (size_t)t * NODE_STRIDE;
    int* srt = sorted + (size_t)t * E_EDGES;
    __shared__ int cnt[BSPAN];     // counts -> local cursor
    __shared__ int begs[BSPAN];    // local exclusive offsets (stable)
    __shared__ int sums[256];
    int tid = threadIdx.x;

    for (int j = tid; j < BSPAN; j += 256) cnt[j] = 0;
    __syncthreads();
    for (int e = ebeg + tid; e < eend; e += 256)
        atomicAdd(&cnt[ebuf[e].y - node0], 1);
    __syncthreads();

    const int chunk = (BSPAN + 255) / 256;   // 19
    int cbeg = tid * chunk;
    int cend = min(cbeg + chunk, BSPAN);
    int s = 0;
    for (int j = cbeg; j < cend; j++) s += cnt[j];
    sums[tid] = s;
    __syncthreads();
    for (int d = 1; d < 256; d <<= 1) {
        int v = (tid >= d) ? sums[tid - d] : 0;
        __syncthreads();
        sums[tid] += v;
        __syncthreads();
    }
    int run = (tid == 0) ? 0 : sums[tid - 1];
    for (int j = cbeg; j < cend; j++) {
        int c = cnt[j];
        begs[j] = run;
        cnt[j] = run;                // cursor
        run += c;
    }
    __syncthreads();

    for (int e = ebeg + tid; e < eend; e += 256) {
        int2 en = ebuf[e];
        int pos = atomicAdd(&cnt[en.y - node0], 1);
        srt[ebeg + pos] = en.x;
    }
    __syncthreads();

    // emit meta: deg, global beg, first two payloads (read back via cache)
    for (int j = tid; j < nodes; j += 256) {
        int lbeg = begs[j];
        int deg = cnt[j] - lbeg;     // cursor end - start
        int gbeg = ebeg + lbeg;
        int4 m;
        m.x = deg;
        m.y = gbeg;
        m.z = (deg > 0) ? srt[gbeg] : 0;
        m.w = (deg > 1) ? srt[gbeg + 1] : 0;
        mt[node0 + j] = m;
    }
}

// ============ Per-step fused aggregation + residual (gather, no atomics) ====
// emb_out[n] = emb_in[n] + mean_{e in bucket(n)} emb_in[src_e] * rel[cat_e]
__global__ __launch_bounds__(256) void fused_agg(
    const float* __restrict__ emb_in, float* __restrict__ emb_out,
    const float* __restrict__ rel_emb, const int4* __restrict__ meta,
    const int* __restrict__ sorted) {
    int g = threadIdx.x >> 5;
    int lane = threadIdx.x & 31;
    int node = blockIdx.x * NPB + g;
    if (node >= N_NODES) return;
    bool act = lane < D4;
    int4 m = meta[node];                 // broadcast: deg, beg, p0, p1
    int deg = m.x;
    float4 own = act ? ((const float4*)(emb_in + (size_t)node * DIM))[lane]
                     : make_float4(0.f, 0.f, 0.f, 0.f);
    float4 acc = make_float4(0.f, 0.f, 0.f, 0.f);
    if (deg > 0 && act) {
        float4 m0 = ((const float4*)(emb_in + (size_t)(m.z & 0x3FFFF) * DIM))[lane];
        float4 r0 = ((const float4*)(rel_emb + (size_t)(m.z >> 18) * DIM))[lane];
        float4 m1, r1;
        if (deg > 1) {
            m1 = ((const float4*)(emb_in + (size_t)(m.w & 0x3FFFF) * DIM))[lane];
            r1 = ((const float4*)(rel_emb + (size_t)(m.w >> 18) * DIM))[lane];
        }
        acc.x += m0.x * r0.x; acc.y += m0.y * r0.y;
        acc.z += m0.z * r0.z; acc.w += m0.w * r0.w;
        if (deg > 1) {
            acc.x += m1.x * r1.x; acc.y += m1.y * r1.y;
            acc.z += m1.z * r1.z; acc.w += m1.w * r1.w;
        }
    }
    // overflow path (deg > 2): walk CSR slice
    for (int e = m.y + 2; e < m.y + deg; e++) {
        int p = sorted[e];
        if (act) {
            float4 mm = ((const float4*)(emb_in + (size_t)(p & 0x3FFFF) * DIM))[lane];
            float4 rr = ((const float4*)(rel_emb + (size_t)(p >> 18) * DIM))[lane];
            acc.x += mm.x * rr.x; acc.y += mm.y * rr.y;
            acc.z += mm.z * rr.z; acc.w += mm.w * rr.w;
        }
    }
    if (act) {
        float inv = (deg > 0) ? 1.0f / (float)deg : 0.0f;
        own.x += acc.x * inv; own.y += acc.y * inv;
        own.z += acc.z * inv; own.w += acc.w * inv;
        ((float4*)(emb_out + (size_t)node * DIM))[lane] = own;
    }
}

// ============ LSTM on seeds (x from emb_new, h_prev from emb_old) ===========
__global__ __launch_bounds__(512) void lstm_kernel(
    const float* __restrict__ emb_new, const float* __restrict__ emb_old,
    const float* __restrict__ c_state, const int* __restrict__ seeds,
    const float* __restrict__ W_ih, const float* __restrict__ W_hh,
    const float* __restrict__ b_ih, const float* __restrict__ b_hh,
    float* __restrict__ h_out, float* __restrict__ c_out) {
    __shared__ __align__(16) float xs[SPB][DIM];
    __shared__ __align__(16) float hs[SPB][DIM];
    __shared__ float gates[SPB][4 * DIM];
    int tid = threadIdx.x;
    int base = blockIdx.x * SPB;

    for (int idx = tid; idx < SPB * DIM; idx += 512) {
        int s = idx / DIM, d = idx - s * DIM;
        int node = seeds[base + s];
        xs[s][d] = emb_new[(size_t)node * DIM + d];
        hs[s][d] = emb_old[(size_t)node * DIM + d];
    }
    __syncthreads();

    if (tid < 4 * DIM) {
        int j = tid;
        float acc[SPB];
#pragma unroll
        for (int s = 0; s < SPB; s++) acc[s] = 0.0f;
        const float4* wi = (const float4*)(W_ih + (size_t)j * DIM);
        const float4* wh = (const float4*)(W_hh + (size_t)j * DIM);
        for (int dc = 0; dc < D4; dc++) {
            float4 a = wi[dc], b = wh[dc];
#pragma unroll
            for (int s = 0; s < SPB; s++) {
                float4 x = ((const float4*)xs[s])[dc];
                float4 h = ((const float4*)hs[s])[dc];
                acc[s] += x.x * a.x + x.y * a.y + x.z * a.z + x.w * a.w
                        + h.x * b.x + h.y * b.y + h.z * b.z + h.w * b.w;
            }
        }
        float bb = b_ih[j] + b_hh[j];
#pragma unroll
        for (int s = 0; s < SPB; s++) gates[s][j] = acc[s] + bb;
    }
    __syncthreads();

    for (int idx = tid; idx < SPB * DIM; idx += 512) {
        int s = idx / DIM, d = idx - s * DIM;
        int node = seeds[base + s];
        float ig = gates[s][d];
        float fg = gates[s][DIM + d];
        float gg = gates[s][2 * DIM + d];
        float og = gates[s][3 * DIM + d];
        float cp = c_state[(size_t)node * DIM + d];
        float cn = sigmoidf_(fg) * cp + sigmoidf_(ig) * tanhf(gg);
        float hn = sigmoidf_(og) * tanhf(cn);
        h_out[(size_t)(base + s) * DIM + d] = hn;
        c_out[(size_t)(base + s) * DIM + d] = cn;
    }
}

// duplicate seeds write identical values -> benign
__global__ __launch_bounds__(256) void scatter_seed(
    float* __restrict__ emb, float* __restrict__ c_state,
    const int* __restrict__ seeds,
    const float* __restrict__ h_new, const float* __restrict__ c_new) {
    int i = blockIdx.x * blockDim.x + threadIdx.x;  // over S*D4
    int sd = i / D4, q = i - sd * D4;
    int node = seeds[sd];
    ((float4*)(emb + (size_t)node * DIM))[q] =
        ((const float4*)(h_new + (size_t)sd * DIM))[q];
    ((float4*)(c_state + (size_t)node * DIM))[q] =
        ((const float4*)(c_new + (size_t)sd * DIM))[q];
}

// ============ Scoring ============
__global__ __launch_bounds__(64) void score_kernel(
    const float* __restrict__ seed_h, const float* __restrict__ emb,
    const int* __restrict__ cand_idx, float* __restrict__ out) {
    int n = blockIdx.x;
    int lane = threadIdx.x;
    float u0 = seed_h[(size_t)n * DIM + lane];
    float u1 = (lane + 64 < DIM) ? seed_h[(size_t)n * DIM + lane + 64] : 0.0f;
    for (int k = 0; k < K_CAND; k++) {
        int node = cand_idx[n * K_CAND + k];
        const float* ce = emb + (size_t)node * DIM;
        float p = u0 * ce[lane];
        if (lane + 64 < DIM) p += u1 * ce[lane + 64];
        for (int off = 32; off > 0; off >>= 1) p += __shfl_down(p, off);
        if (lane == 0) out[n * K_CAND + k] = p;
    }
}

extern "C" void kernel_launch(void* const* d_in, const int* in_sizes, int n_in,
                              void* d_out, int out_size, void* d_ws, size_t ws_size,
                              hipStream_t stream) {
    const float* node_emb = (const float*)d_in[0];
    const float* cx       = (const float*)d_in[1];
    const float* rel_emb  = (const float*)d_in[2];
    const float* W_ih     = (const float*)d_in[3];
    const float* W_hh     = (const float*)d_in[4];
    const float* b_ih     = (const float*)d_in[5];
    const float* b_hh     = (const float*)d_in[6];
    const int*   src      = (const int*)d_in[7];
    const int*   dst      = (const int*)d_in[8];
    const int*   cat      = (const int*)d_in[9];
    const int*   seeds    = (const int*)d_in[10];
    const int*   cand     = (const int*)d_in[11];
    float* out = (float*)d_out;

    char* wsb = (char*)d_ws;
    float* emb_a = (float*)wsb; wsb += sizeof(float) * (size_t)N_NODES * DIM;
    float* emb_b = (float*)wsb; wsb += sizeof(float) * (size_t)N_NODES * DIM;
    float* cst   = (float*)wsb; wsb += sizeof(float) * (size_t)N_NODES * DIM;
    float* cnew  = (float*)wsb; wsb += sizeof(float) * (size_t)S_SEEDS * DIM;
    float* seedh = (float*)wsb; wsb += sizeof(float) * (size_t)T_STEPS * S_SEEDS * DIM;
    int4* meta   = (int4*)wsb; wsb += sizeof(int4) * (size_t)T_STEPS * NODE_STRIDE;
    int* sorted  = (int*)wsb; wsb += sizeof(int) * (size_t)T_STEPS * E_EDGES;
    int* ccnt    = (int*)wsb; wsb += sizeof(int) * T_STEPS * CB;
    int* ccur    = (int*)wsb; wsb += sizeof(int) * T_STEPS * CB;
    int* coffs   = (int*)wsb; wsb += sizeof(int) * T_STEPS * (CB + 1);
    // coarse entry buffer (33.6 MB) aliases emb_b: dead until first fused_agg
    int2* cbuf = (int2*)emb_b;

    // ---- CSR build for all 16 steps (two-level counting sort) ----
    hipMemsetAsync(ccnt, 0, sizeof(int) * T_STEPS * CB, stream);
    coarse_hist<<<T_STEPS * 1024, 256, 0, stream>>>(dst, ccnt);
    coarse_scan<<<T_STEPS, 64, 0, stream>>>(ccnt, coffs, ccur);
    coarse_scatter<<<T_STEPS * 1024, 256, 0, stream>>>(src, dst, cat, ccur, cbuf);
    fine_build<<<T_STEPS * CB, 256, 0, stream>>>(cbuf, coffs, meta, sorted);

    hipMemcpyAsync(emb_a, node_emb, sizeof(float) * (size_t)N_NODES * DIM,
                   hipMemcpyDeviceToDevice, stream);
    hipMemcpyAsync(cst, cx, sizeof(float) * (size_t)N_NODES * DIM,
                   hipMemcpyDeviceToDevice, stream);

    float* cur = emb_a;
    float* nxt = emb_b;
    for (int t = 0; t < T_STEPS; t++) {
        fused_agg<<<(N_NODES + NPB - 1) / NPB, 256, 0, stream>>>(
            cur, nxt, rel_emb,
            meta + (size_t)t * NODE_STRIDE, sorted + (size_t)t * E_EDGES);
        lstm_kernel<<<S_SEEDS / SPB, 512, 0, stream>>>(
            nxt, cur, cst, seeds + (size_t)t * S_SEEDS,
            W_ih, W_hh, b_ih, b_hh,
            seedh + (size_t)t * S_SEEDS * DIM, cnew);
        scatter_seed<<<(S_SEEDS * D4) / 256, 256, 0, stream>>>(
            nxt, cst, seeds + (size_t)t * S_SEEDS,
            seedh + (size_t)t * S_SEEDS * DIM, cnew);
        float* tmp = cur; cur = nxt; nxt = tmp;
    }
    score_kernel<<<T_STEPS * S_SEEDS, 64, 0, stream>>>(seedh, cur, cand, out);
}

// Round 7
// 1543.423 us; speedup vs baseline: 5.3903x; 1.0952x over previous
//
#include <hip/hip_runtime.h>
#include <math.h>

#define N_NODES 150000
#define NODE_STRIDE 150016   // padded per-step stride for meta array
#define DIM 100
#define D4 25                // DIM/4 float4 chunks
#define T_STEPS 16
#define E_EDGES 262144
#define S_SEEDS 4096
#define K_CAND 9
#define SPB 16               // seeds per LSTM block
#define NPB 8                // nodes per fused_agg block (8 groups x 32 lanes)

#define CB 64                // coarse buckets per step
#define BSPAN 2344           // nodes per coarse bucket; 64*2344 = 150016 >= N
#define EPT 8                // edges per thread in coarse passes
#define EPB (256 * EPT)      // 2048 edges per coarse block
#define CBLK (E_EDGES / EPB) // 128 coarse blocks per step

__device__ __forceinline__ float sigmoidf_(float x) {
    return 1.0f / (1.0f + __expf(-x));
}

// ============ CSR build: atomic-free two-level counting sort ============

// Pass 1: per-(block,bucket) histogram -> bh[t][blk][b] (plain stores)
__global__ __launch_bounds__(256) void coarse_hist(
    const int* __restrict__ dst, int* __restrict__ bh) {
    int t = blockIdx.x / CBLK;
    int blk = blockIdx.x % CBLK;
    int base = t * E_EDGES + blk * EPB;
    int tid = threadIdx.x;
    __shared__ int h[CB];
    if (tid < CB) h[tid] = 0;
    __syncthreads();
#pragma unroll
    for (int e = 0; e < EPT; e++) {
        int d = dst[base + e * 256 + tid];
        atomicAdd(&h[d / BSPAN], 1);
    }
    __syncthreads();
    if (tid < CB) bh[(t * CBLK + blk) * CB + tid] = h[tid];
}

// Pass 2: per step, scan bh over blocks (per bucket) + bucket scan -> coffs.
// bh becomes within-bucket exclusive per-block offsets.
__global__ __launch_bounds__(64) void scan_bh(
    int* __restrict__ bh, int* __restrict__ coffs) {
    int t = blockIdx.x;
    int b = threadIdx.x;          // 64 threads = 64 buckets
    int run = 0;
    for (int blk = 0; blk < CBLK; blk++) {
        int idx = (t * CBLK + blk) * CB + b;
        int v = bh[idx];
        bh[idx] = run;
        run += v;
    }
    __shared__ int tot[CB];
    tot[b] = run;
    __syncthreads();
    if (b == 0) {
        int r = 0;
        for (int i = 0; i < CB; i++) { int c = tot[i]; tot[i] = r; r += c; }
    }
    __syncthreads();
    coffs[t * (CB + 1) + b] = tot[b];
    if (b == 0) coffs[t * (CB + 1) + CB] = E_EDGES;
}

// Pass 3: scatter into coarse buckets, zero global atomics (ranks in regs)
__global__ __launch_bounds__(256) void coarse_scatter(
    const int* __restrict__ src, const int* __restrict__ dst,
    const int* __restrict__ cat, const int* __restrict__ bh,
    const int* __restrict__ coffs, int2* __restrict__ cbuf) {
    int t = blockIdx.x / CBLK;
    int blk = blockIdx.x % CBLK;
    int base = t * E_EDGES + blk * EPB;
    int tid = threadIdx.x;
    __shared__ int h[CB];
    __shared__ int gbase[CB];
    if (tid < CB) h[tid] = 0;
    __syncthreads();
    int rank[EPT], bb[EPT], dd[EPT];
#pragma unroll
    for (int e = 0; e < EPT; e++) {
        int d = dst[base + e * 256 + tid];
        int b = d / BSPAN;
        dd[e] = d; bb[e] = b;
        rank[e] = atomicAdd(&h[b], 1);
    }
    __syncthreads();
    if (tid < CB)
        gbase[tid] = coffs[t * (CB + 1) + tid] + bh[(t * CBLK + blk) * CB + tid];
    __syncthreads();
#pragma unroll
    for (int e = 0; e < EPT; e++) {
        int i = base + e * 256 + tid;
        int2 en;
        en.x = src[i] | (cat[i] << 18);
        en.y = dd[e];
        cbuf[(size_t)t * E_EDGES + gbase[bb[e]] + rank[e]] = en;
    }
}

// Pass 4: per (step,bucket) fine counting sort in LDS; emits sorted[] and
// meta = {beg | deg<<19, p0, p1, p2} (fast path deg<=3).
__global__ __launch_bounds__(256) void fine_build(
    const int2* __restrict__ cbuf, const int* __restrict__ coffs,
    int4* __restrict__ meta, int* __restrict__ sorted) {
    int t = blockIdx.x >> 6;
    int b = blockIdx.x & 63;
    int node0 = b * BSPAN;
    int nodes = min(BSPAN, N_NODES - node0);
    int ebeg = coffs[t * (CB + 1) + b];
    int eend = coffs[t * (CB + 1) + b + 1];
    const int2* ebuf = cbuf + (size_t)t * E_EDGES;
    int4* mt = meta + (size_t)t * NODE_STRIDE;
    int* srt = sorted + (size_t)t * E_EDGES;
    __shared__ int cnt[BSPAN];     // counts -> cursor
    __shared__ int begs[BSPAN];    // local exclusive offsets
    __shared__ int sums[256];
    int tid = threadIdx.x;

    for (int j = tid; j < BSPAN; j += 256) cnt[j] = 0;
    __syncthreads();
    for (int e = ebeg + tid; e < eend; e += 256)
        atomicAdd(&cnt[ebuf[e].y - node0], 1);
    __syncthreads();

    const int chunk = (BSPAN + 255) / 256;   // 10
    int cbeg = tid * chunk;
    int cend = min(cbeg + chunk, BSPAN);
    int s = 0;
    for (int j = cbeg; j < cend; j++) s += cnt[j];
    sums[tid] = s;
    __syncthreads();
    for (int d = 1; d < 256; d <<= 1) {
        int v = (tid >= d) ? sums[tid - d] : 0;
        __syncthreads();
        sums[tid] += v;
        __syncthreads();
    }
    int run = (tid == 0) ? 0 : sums[tid - 1];
    for (int j = cbeg; j < cend; j++) {
        int c = cnt[j];
        begs[j] = run;
        cnt[j] = run;                // cursor
        run += c;
    }
    __syncthreads();

    for (int e = ebeg + tid; e < eend; e += 256) {
        int2 en = ebuf[e];
        int pos = atomicAdd(&cnt[en.y - node0], 1);
        srt[ebeg + pos] = en.x;
    }
    __syncthreads();

    for (int j = tid; j < nodes; j += 256) {
        int lbeg = begs[j];
        int deg = cnt[j] - lbeg;
        int gbeg = ebeg + lbeg;
        int4 m;
        m.x = gbeg | (deg << 19);    // gbeg <= 2^18, deg < 2^13
        m.y = (deg > 0) ? srt[gbeg] : 0;
        m.z = (deg > 1) ? srt[gbeg + 1] : 0;
        m.w = (deg > 2) ? srt[gbeg + 2] : 0;
        mt[node0 + j] = m;
    }
}

// ============ Per-step fused aggregation + residual (gather, no atomics) ====
// emb_out[n] = emb_in[n] + mean_{e in bucket(n)} emb_in[src_e] * rel[cat_e]
__global__ __launch_bounds__(256) void fused_agg(
    const float* __restrict__ emb_in, float* __restrict__ emb_out,
    const float* __restrict__ rel_emb, const int4* __restrict__ meta,
    const int* __restrict__ sorted) {
    int g = threadIdx.x >> 5;
    int lane = threadIdx.x & 31;
    int node = blockIdx.x * NPB + g;
    if (node >= N_NODES) return;
    bool act = lane < D4;
    float4 own = act ? ((const float4*)(emb_in + (size_t)node * DIM))[lane]
                     : make_float4(0.f, 0.f, 0.f, 0.f);
    int4 m = meta[node];                 // broadcast: beg|deg, p0, p1, p2
    int deg = ((unsigned)m.x) >> 19;
    int beg = m.x & 0x7FFFF;
    float4 acc = make_float4(0.f, 0.f, 0.f, 0.f);
    if (act) {
        if (deg > 0) {
            float4 mm = ((const float4*)(emb_in + (size_t)(m.y & 0x3FFFF) * DIM))[lane];
            float4 rr = ((const float4*)(rel_emb + (size_t)(m.y >> 18) * DIM))[lane];
            acc.x += mm.x * rr.x; acc.y += mm.y * rr.y;
            acc.z += mm.z * rr.z; acc.w += mm.w * rr.w;
        }
        if (deg > 1) {
            float4 mm = ((const float4*)(emb_in + (size_t)(m.z & 0x3FFFF) * DIM))[lane];
            float4 rr = ((const float4*)(rel_emb + (size_t)(m.z >> 18) * DIM))[lane];
            acc.x += mm.x * rr.x; acc.y += mm.y * rr.y;
            acc.z += mm.z * rr.z; acc.w += mm.w * rr.w;
        }
        if (deg > 2) {
            float4 mm = ((const float4*)(emb_in + (size_t)(m.w & 0x3FFFF) * DIM))[lane];
            float4 rr = ((const float4*)(rel_emb + (size_t)(m.w >> 18) * DIM))[lane];
            acc.x += mm.x * rr.x; acc.y += mm.y * rr.y;
            acc.z += mm.z * rr.z; acc.w += mm.w * rr.w;
        }
    }
    // overflow path (deg > 3): walk CSR slice
    for (int e = beg + 3; e < beg + deg; e++) {
        int p = sorted[e];
        if (act) {
            float4 mm = ((const float4*)(emb_in + (size_t)(p & 0x3FFFF) * DIM))[lane];
            float4 rr = ((const float4*)(rel_emb + (size_t)(p >> 18) * DIM))[lane];
            acc.x += mm.x * rr.x; acc.y += mm.y * rr.y;
            acc.z += mm.z * rr.z; acc.w += mm.w * rr.w;
        }
    }
    if (act) {
        float inv = (deg > 0) ? 1.0f / (float)deg : 0.0f;
        own.x += acc.x * inv; own.y += acc.y * inv;
        own.z += acc.z * inv; own.w += acc.w * inv;
        ((float4*)(emb_out + (size_t)node * DIM))[lane] = own;
    }
}

// ============ LSTM on seeds (x from emb_new, h_prev from emb_old) ===========
__global__ __launch_bounds__(512) void lstm_kernel(
    const float* __restrict__ emb_new, const float* __restrict__ emb_old,
    const float* __restrict__ c_state, const int* __restrict__ seeds,
    const float* __restrict__ W_ih, const float* __restrict__ W_hh,
    const float* __restrict__ b_ih, const float* __restrict__ b_hh,
    float* __restrict__ h_out, float* __restrict__ c_out) {
    __shared__ __align__(16) float xs[SPB][DIM];
    __shared__ __align__(16) float hs[SPB][DIM];
    __shared__ float gates[SPB][4 * DIM];
    int tid = threadIdx.x;
    int base = blockIdx.x * SPB;

    for (int idx = tid; idx < SPB * DIM; idx += 512) {
        int s = idx / DIM, d = idx - s * DIM;
        int node = seeds[base + s];
        xs[s][d] = emb_new[(size_t)node * DIM + d];
        hs[s][d] = emb_old[(size_t)node * DIM + d];
    }
    __syncthreads();

    if (tid < 4 * DIM) {
        int j = tid;
        float acc[SPB];
#pragma unroll
        for (int s = 0; s < SPB; s++) acc[s] = 0.0f;
        const float4* wi = (const float4*)(W_ih + (size_t)j * DIM);
        const float4* wh = (const float4*)(W_hh + (size_t)j * DIM);
        for (int dc = 0; dc < D4; dc++) {
            float4 a = wi[dc], b = wh[dc];
#pragma unroll
            for (int s = 0; s < SPB; s++) {
                float4 x = ((const float4*)xs[s])[dc];
                float4 h = ((const float4*)hs[s])[dc];
                acc[s] += x.x * a.x + x.y * a.y + x.z * a.z + x.w * a.w
                        + h.x * b.x + h.y * b.y + h.z * b.z + h.w * b.w;
            }
        }
        float bb = b_ih[j] + b_hh[j];
#pragma unroll
        for (int s = 0; s < SPB; s++) gates[s][j] = acc[s] + bb;
    }
    __syncthreads();

    for (int idx = tid; idx < SPB * DIM; idx += 512) {
        int s = idx / DIM, d = idx - s * DIM;
        int node = seeds[base + s];
        float ig = gates[s][d];
        float fg = gates[s][DIM + d];
        float gg = gates[s][2 * DIM + d];
        float og = gates[s][3 * DIM + d];
        float cp = c_state[(size_t)node * DIM + d];
        float cn = sigmoidf_(fg) * cp + sigmoidf_(ig) * tanhf(gg);
        float hn = sigmoidf_(og) * tanhf(cn);
        h_out[(size_t)(base + s) * DIM + d] = hn;
        c_out[(size_t)(base + s) * DIM + d] = cn;
    }
}

// duplicate seeds write identical values -> benign
__global__ __launch_bounds__(256) void scatter_seed(
    float* __restrict__ emb, float* __restrict__ c_state,
    const int* __restrict__ seeds,
    const float* __restrict__ h_new, const float* __restrict__ c_new) {
    int i = blockIdx.x * blockDim.x + threadIdx.x;  // over S*D4
    int sd = i / D4, q = i - sd * D4;
    int node = seeds[sd];
    ((float4*)(emb + (size_t)node * DIM))[q] =
        ((const float4*)(h_new + (size_t)sd * DIM))[q];
    ((float4*)(c_state + (size_t)node * DIM))[q] =
        ((const float4*)(c_new + (size_t)sd * DIM))[q];
}

// ============ Scoring ============
__global__ __launch_bounds__(64) void score_kernel(
    const float* __restrict__ seed_h, const float* __restrict__ emb,
    const int* __restrict__ cand_idx, float* __restrict__ out) {
    int n = blockIdx.x;
    int lane = threadIdx.x;
    float u0 = seed_h[(size_t)n * DIM + lane];
    float u1 = (lane + 64 < DIM) ? seed_h[(size_t)n * DIM + lane + 64] : 0.0f;
    for (int k = 0; k < K_CAND; k++) {
        int node = cand_idx[n * K_CAND + k];
        const float* ce = emb + (size_t)node * DIM;
        float p = u0 * ce[lane];
        if (lane + 64 < DIM) p += u1 * ce[lane + 64];
        for (int off = 32; off > 0; off >>= 1) p += __shfl_down(p, off);
        if (lane == 0) out[n * K_CAND + k] = p;
    }
}

extern "C" void kernel_launch(void* const* d_in, const int* in_sizes, int n_in,
                              void* d_out, int out_size, void* d_ws, size_t ws_size,
                              hipStream_t stream) {
    const float* node_emb = (const float*)d_in[0];
    const float* cx       = (const float*)d_in[1];
    const float* rel_emb  = (const float*)d_in[2];
    const float* W_ih     = (const float*)d_in[3];
    const float* W_hh     = (const float*)d_in[4];
    const float* b_ih     = (const float*)d_in[5];
    const float* b_hh     = (const float*)d_in[6];
    const int*   src      = (const int*)d_in[7];
    const int*   dst      = (const int*)d_in[8];
    const int*   cat      = (const int*)d_in[9];
    const int*   seeds    = (const int*)d_in[10];
    const int*   cand     = (const int*)d_in[11];
    float* out = (float*)d_out;

    char* wsb = (char*)d_ws;
    float* emb_a = (float*)wsb; wsb += sizeof(float) * (size_t)N_NODES * DIM;
    float* emb_b = (float*)wsb; wsb += sizeof(float) * (size_t)N_NODES * DIM;
    float* cst   = (float*)wsb; wsb += sizeof(float) * (size_t)N_NODES * DIM;
    float* cnew  = (float*)wsb; wsb += sizeof(float) * (size_t)S_SEEDS * DIM;
    float* seedh = (float*)wsb; wsb += sizeof(float) * (size_t)T_STEPS * S_SEEDS * DIM;
    int4* meta   = (int4*)wsb; wsb += sizeof(int4) * (size_t)T_STEPS * NODE_STRIDE;
    int* sorted  = (int*)wsb; wsb += sizeof(int) * (size_t)T_STEPS * E_EDGES;
    int* bh      = (int*)wsb; wsb += sizeof(int) * (size_t)T_STEPS * CBLK * CB;
    int* coffs   = (int*)wsb; wsb += sizeof(int) * T_STEPS * (CB + 1);
    // coarse entry buffer (33.6 MB) aliases emb_b: dead until first fused_agg
    int2* cbuf = (int2*)emb_b;

    // ---- CSR build for all 16 steps (atomic-free two-level sort) ----
    coarse_hist<<<T_STEPS * CBLK, 256, 0, stream>>>(dst, bh);
    scan_bh<<<T_STEPS, 64, 0, stream>>>(bh, coffs);
    coarse_scatter<<<T_STEPS * CBLK, 256, 0, stream>>>(
        src, dst, cat, bh, coffs, cbuf);
    fine_build<<<T_STEPS * CB, 256, 0, stream>>>(cbuf, coffs, meta, sorted);

    hipMemcpyAsync(cst, cx, sizeof(float) * (size_t)N_NODES * DIM,
                   hipMemcpyDeviceToDevice, stream);

    const float* cur = node_emb;     // t=0 reads input table directly
    float* bufs[2] = {emb_b, emb_a};
    for (int t = 0; t < T_STEPS; t++) {
        float* nxt = bufs[t & 1];
        fused_agg<<<(N_NODES + NPB - 1) / NPB, 256, 0, stream>>>(
            cur, nxt, rel_emb,
            meta + (size_t)t * NODE_STRIDE, sorted + (size_t)t * E_EDGES);
        lstm_kernel<<<S_SEEDS / SPB, 512, 0, stream>>>(
            nxt, cur, cst, seeds + (size_t)t * S_SEEDS,
            W_ih, W_hh, b_ih, b_hh,
            seedh + (size_t)t * S_SEEDS * DIM, cnew);
        scatter_seed<<<(S_SEEDS * D4) / 256, 256, 0, stream>>>(
            nxt, cst, seeds + (size_t)t * S_SEEDS,
            seedh + (size_t)t * S_SEEDS * DIM, cnew);
        cur = nxt;
    }
    score_kernel<<<T_STEPS * S_SEEDS, 64, 0, stream>>>(seedh, cur, cand, out);
}